// Round 1
// baseline (17382.623 us; speedup 1.0000x reference)
//
#include <hip/hip_runtime.h>

// SCNN message passing: 4 sequential scan passes (2 vertical, 2 horizontal),
// each pass: out[i] = x[i] + relu(conv1d_C128K9(out[i+1])) scanning from the
// last row/col down to 0 (all passes reverse=True in the reference).
//
// Baseline strategy: one kernel launch per scan step (636 total), operating
// in-place on d_out. Unified step kernel handles both directions via
// (stride S, length L) parameters.

#define C_   128
#define H_   128
#define W_   192
#define N_   4
#define K_   9
#define HW_  (H_ * W_)
#define CHW_ (C_ * HW_)

// One scan step:
//   data[n, co, base_out + t*S] += relu( sum_{ci,k} data[n, ci, base_prev + (t+k-4)*S] * wgt[co,ci,k] )
// Block: 256 threads = 4 co x 64 t positions. Grid: (L/64, C/4, N).
__global__ __launch_bounds__(256) void scnn_step(float* __restrict__ data,
                                                 const float* __restrict__ wgt,
                                                 int base_out, int base_prev,
                                                 int S, int L) {
    __shared__ float pl[C_][72];     // prev row tile: 64 positions + 4 halo each side
    __shared__ float wl[4][C_][K_];  // weights for this block's 4 output channels

    const int tid = threadIdx.x;
    const int t0  = blockIdx.x * 64;
    const int co0 = blockIdx.y * 4;
    const int n   = blockIdx.z;
    const float* prev = data + (size_t)n * CHW_ + base_prev;

    // Stage prev tile [ci][w], w in [0,72) maps to scan-line position t = t0 - 4 + w.
    for (int idx = tid; idx < C_ * 72; idx += 256) {
        int ci = idx / 72, w = idx % 72;
        int t = t0 - 4 + w;
        float v = 0.f;
        if (t >= 0 && t < L) v = prev[(size_t)ci * HW_ + (size_t)t * S];
        pl[ci][w] = v;
    }
    // Stage weights for 4 consecutive co (coalesced global, linear LDS).
    for (int idx = tid; idx < 4 * C_ * K_; idx += 256) {
        int col = idx / (C_ * K_);
        int rem = idx % (C_ * K_);
        ((float*)wl)[idx] = wgt[(size_t)(co0 + col) * (C_ * K_) + rem];
    }
    __syncthreads();

    const int col = tid >> 6;  // co within block (uniform per wave -> LDS broadcast)
    const int tw  = tid & 63;  // position within tile (consecutive lanes -> no bank conflict)

    float acc = 0.f;
    for (int ci = 0; ci < C_; ++ci) {
        #pragma unroll
        for (int k = 0; k < K_; ++k)
            acc = fmaf(wl[col][ci][k], pl[ci][tw + k], acc);
    }

    size_t opos = (size_t)n * CHW_ + (size_t)(co0 + col) * HW_
                + (size_t)base_out + (size_t)(t0 + tw) * S;
    data[opos] = data[opos] + fmaxf(acc, 0.f);
}

extern "C" void kernel_launch(void* const* d_in, const int* in_sizes, int n_in,
                              void* d_out, int out_size, void* d_ws, size_t ws_size,
                              hipStream_t stream) {
    const float* x    = (const float*)d_in[0];
    const float* w_ud = (const float*)d_in[1];
    const float* w_du = (const float*)d_in[2];
    const float* w_lr = (const float*)d_in[3];
    const float* w_rl = (const float*)d_in[4];
    float* out = (float*)d_out;

    // out <- x, then all passes update in place.
    hipMemcpyAsync(out, x, sizeof(float) * (size_t)N_ * CHW_,
                   hipMemcpyDeviceToDevice, stream);

    // Passes 1,2: vertical (scan over h, conv along w: stride 1, length W).
    {
        dim3 grid(W_ / 64, C_ / 4, N_);
        for (int p = 0; p < 2; ++p) {
            const float* w = (p == 0) ? w_ud : w_du;
            for (int i = H_ - 2; i >= 0; --i)
                scnn_step<<<grid, 256, 0, stream>>>(out, w, i * W_, (i + 1) * W_, 1, W_);
        }
    }
    // Passes 3,4: horizontal (scan over w, conv along h: stride W, length H).
    {
        dim3 grid(H_ / 64, C_ / 4, N_);
        for (int p = 0; p < 2; ++p) {
            const float* w = (p == 0) ? w_lr : w_rl;
            for (int j = W_ - 2; j >= 0; --j)
                scnn_step<<<grid, 256, 0, stream>>>(out, w, j, j + 1, W_, H_);
        }
    }
}